// Round 6
// baseline (451.347 us; speedup 1.0000x reference)
//
#include <hip/hip_runtime.h>
#include <hip/hip_bf16.h>

#define S_LEN 2048
#define NB    32      // batch
#define EMB   1024
#define ATT   512
#define HID   1024

typedef float f32x4  __attribute__((ext_vector_type(4)));
typedef short s16x4  __attribute__((ext_vector_type(4)));
typedef short s16x8  __attribute__((ext_vector_type(8)));

static __device__ __forceinline__ short f2bf(float f) {
    return __builtin_bit_cast(short, __float2bfloat16(f));
}
static __device__ __forceinline__ float tanh_fast(float x) {
    float e = __expf(2.0f * x);
    return 1.0f - 2.0f / (e + 1.0f);
}

#define GLOAD_LDS16(gp, lp)                                                   \
    __builtin_amdgcn_global_load_lds(                                         \
        (const __attribute__((address_space(1))) void*)(gp),                  \
        (__attribute__((address_space(3))) void*)(uintptr_t)(lp), 16, 0, 0)

// ---------------- K1: hid_comb[b][a] = hid[b,:]@W_hid[:,a] + b_hid[a] + b_emb[a]
__global__ void k_hidcomb(const float* __restrict__ hid,
                          const float* __restrict__ W_hid,
                          const float* __restrict__ b_hid,
                          const float* __restrict__ b_emb,
                          float* __restrict__ hid_comb) {
    int gid = blockIdx.x * 256 + threadIdx.x;   // 32*512 = 16384
    int b = gid >> 9, a = gid & 511;
    const float* hr = hid + b * HID;
    float acc = 0.f;
#pragma unroll 4
    for (int k = 0; k < HID; ++k) acc += hr[k] * W_hid[k * ATT + a];
    hid_comb[gid] = acc + b_hid[a] + b_emb[a];
}

// ---------------- K2: W_T[a][k] = bf16(W_emb[k][a])
__global__ void k_wt(const float* __restrict__ W, unsigned short* __restrict__ WT) {
    __shared__ float tile[32][33];
    int k0 = blockIdx.x * 32, a0 = blockIdx.y * 32;
    int tx = threadIdx.x, ty = threadIdx.y;     // 32 x 8
#pragma unroll
    for (int i = 0; i < 32; i += 8)
        tile[ty + i][tx] = W[(size_t)(k0 + ty + i) * ATT + a0 + tx];
    __syncthreads();
#pragma unroll
    for (int i = 0; i < 32; i += 8)
        WT[(size_t)(a0 + ty + i) * HID + k0 + tx] =
            (unsigned short)f2bf(tile[tx][ty + i]);
}

// ---------------- K3: B-resident barrier-free GEMM.
// Block: n-tile 64 cols (whole K=1024 of B in 128KB LDS, loaded once),
// 4 waves x (64 rows x 64 cols), 4 m-tiles of 256 rows per block.
// K-loop: A direct global->reg (2-step prefetch, static P0/P1), cvt->bf16,
// ds_read B frags (proven swizzle), 16 MFMA. NO barriers, NO ds_writes.
// Fused tanh + dot(att_v) epilogue -> part[n][b][s] (8 slices, no atomics).
__global__ __launch_bounds__(256, 1) void k_gemm_scores(
        const float* __restrict__ emb,
        const unsigned short* __restrict__ WT,
        const float* __restrict__ hid_comb,
        const float* __restrict__ att_v,
        float* __restrict__ part) {
    // [kc 0..31][col 0..63][32 k-elems] bf16, swizzled within each (kc,col) row
    __shared__ __align__(16) unsigned short lB[32 * 64 * 32];   // 128 KB

    // bid -> (XCD x, n-tile, m-group). All 8 n-tiles of an m-panel land on the
    // same XCD in the same dispatch round -> A-panel read once into XCD L2.
    int bid  = blockIdx.x;          // 512 blocks
    int x    = bid & 7;             // XCD (dispatch round-robin)
    int slot = bid >> 3;            // 0..63 within XCD
    int n    = slot & 7;            // n-tile 0..7
    int gl   = slot >> 3;           // 0..7
    int g    = x * 8 + gl;          // m-group 0..63 (4 m-tiles of 256 rows each)
    int n0   = n * 64;

    int tid  = threadIdx.x;
    int lane = tid & 63, w = tid >> 6;
    int row_l = lane & 15;          // fragment row (A) / col (B,D)
    int kg    = lane >> 4;          // k-group: k = kg*8 + i

    // ---- stage whole B panel once: 8192 16B-chunks, 32 per thread
#pragma unroll 4
    for (int j = 0; j < 32; ++j) {
        int c = j * 256 + tid;
        int kc = c >> 8, rem = c & 255, col = rem >> 2, pos = rem & 3;
        const unsigned short* gp = WT + (size_t)(n0 + col) * HID + kc * 32
                                      + (pos ^ ((col >> 1) & 3)) * 8;
        GLOAD_LDS16(gp, (char*)lB + c * 16);
    }
    __syncthreads();   // the ONLY barrier (drains vmcnt; B ready & read-only)

    // fragment read byte-offsets within a kc-tile (proven 0-conflict pattern)
    int boff[4];
#pragma unroll
    for (int nf = 0; nf < 4; ++nf) {
        int row = nf * 16 + row_l;
        boff[nf] = row * 64 + ((kg ^ ((row >> 1) & 3)) * 16);
    }
    float vv[4];
#pragma unroll
    for (int nf = 0; nf < 4; ++nf)
        vv[nf] = att_v[n0 + nf * 16 + row_l];

#define ASTEP(SET, KK)                                                         \
    {                                                                          \
        s16x8 af[4];                                                           \
        _Pragma("unroll")                                                      \
        for (int mf = 0; mf < 4; ++mf) {                                       \
            s16x8 r;                                                           \
            r[0] = f2bf(SET[mf][0][0]); r[1] = f2bf(SET[mf][0][1]);            \
            r[2] = f2bf(SET[mf][0][2]); r[3] = f2bf(SET[mf][0][3]);            \
            r[4] = f2bf(SET[mf][1][0]); r[5] = f2bf(SET[mf][1][1]);            \
            r[6] = f2bf(SET[mf][1][2]); r[7] = f2bf(SET[mf][1][3]);            \
            af[mf] = r;                                                        \
        }                                                                      \
        int kl_ = ((KK) + 64) & 1023;   /* refill this set 2 steps ahead */    \
        _Pragma("unroll")                                                      \
        for (int mf = 0; mf < 4; ++mf) {                                       \
            SET[mf][0] = *(const f32x4*)(ap[mf] + kl_);                        \
            SET[mf][1] = *(const f32x4*)(ap[mf] + kl_ + 4);                    \
        }                                                                      \
        const char* pb_ = (const char*)lB + (KK) * 128;  /* kc*4096 */         \
        s16x8 bf[4];                                                           \
        _Pragma("unroll")                                                      \
        for (int nf = 0; nf < 4; ++nf)                                         \
            bf[nf] = *(const s16x8*)(pb_ + boff[nf]);                          \
        _Pragma("unroll")                                                      \
        for (int mf = 0; mf < 4; ++mf)                                         \
            _Pragma("unroll")                                                  \
            for (int nf = 0; nf < 4; ++nf)                                     \
                acc[mf][nf] = __builtin_amdgcn_mfma_f32_16x16x32_bf16(         \
                    af[mf], bf[nf], acc[mf][nf], 0, 0, 0);                     \
    }

    for (int mi = 0; mi < 4; ++mi) {
        size_t mrow = ((size_t)(g * 4 + mi)) * 256 + (size_t)w * 64;
        const float* ap[4];
#pragma unroll
        for (int mf = 0; mf < 4; ++mf)
            ap[mf] = emb + (mrow + mf * 16 + row_l) * EMB + kg * 8;

        // prologue: steps 0 and 1 into the two static prefetch sets
        f32x4 P0[4][2], P1[4][2];
#pragma unroll
        for (int mf = 0; mf < 4; ++mf) {
            P0[mf][0] = *(const f32x4*)(ap[mf]);
            P0[mf][1] = *(const f32x4*)(ap[mf] + 4);
            P1[mf][0] = *(const f32x4*)(ap[mf] + 32);
            P1[mf][1] = *(const f32x4*)(ap[mf] + 36);
        }

        f32x4 acc[4][4] = {};
        for (int it = 0; it < 16; ++it) {
            int kk = it * 64;
            ASTEP(P0, kk)
            ASTEP(P1, kk + 32)
        }

        // ---- epilogue for this m-tile: tanh + dot(att_v) + 16-lane reduce
#pragma unroll
        for (int mf = 0; mf < 4; ++mf) {
#pragma unroll
            for (int j = 0; j < 4; ++j) {
                int m = (g * 4 + mi) * 256 + w * 64 + mf * 16 + kg * 4 + j;
                int b = m & 31;
                int s = m >> 5;
                const float* ad = hid_comb + b * ATT + n0;
                float sum = 0.f;
#pragma unroll
                for (int nf = 0; nf < 4; ++nf) {
                    float xv = acc[mf][nf][j] + ad[nf * 16 + row_l];
                    sum += tanh_fast(xv) * vv[nf];
                }
#pragma unroll
                for (int d = 1; d < 16; d <<= 1)
                    sum += __shfl_xor(sum, d, 64);
                if (row_l == 0)
                    part[n * (NB * S_LEN) + b * S_LEN + s] = sum;
            }
        }
    }
#undef ASTEP
}

// ---------------- K4: softmax over S per batch row (sums the 8 n-slices)
__global__ void k_softmax(const float* __restrict__ part,
                          float* __restrict__ weights) {
    int b = blockIdx.x, tid = threadIdx.x;  // 256 threads
    float v[8];
    float mx = -1e30f;
#pragma unroll
    for (int i = 0; i < 8; ++i) {
        int s = i * 256 + tid;
        float sc = 0.f;
#pragma unroll
        for (int p = 0; p < 8; ++p)
            sc += part[p * (NB * S_LEN) + b * S_LEN + s];
        v[i] = sc;
        mx = fmaxf(mx, sc);
    }
#pragma unroll
    for (int d = 1; d < 64; d <<= 1) mx = fmaxf(mx, __shfl_xor(mx, d, 64));
    __shared__ float sm[4], ss[4];
    if ((tid & 63) == 0) sm[tid >> 6] = mx;
    __syncthreads();
    mx = fmaxf(fmaxf(sm[0], sm[1]), fmaxf(sm[2], sm[3]));
    float sum = 0.f;
#pragma unroll
    for (int i = 0; i < 8; ++i) {
        v[i] = __expf(v[i] - mx);
        sum += v[i];
    }
#pragma unroll
    for (int d = 1; d < 64; d <<= 1) sum += __shfl_xor(sum, d, 64);
    if ((tid & 63) == 0) ss[tid >> 6] = sum;
    __syncthreads();
    sum = ss[0] + ss[1] + ss[2] + ss[3];
    float inv = 1.0f / sum;
#pragma unroll
    for (int i = 0; i < 8; ++i)
        weights[b * S_LEN + i * 256 + tid] = v[i] * inv;
}

// ---------------- K5: context partials over s-chunks (f32 emb)
__global__ void k_ctx1(const float* __restrict__ emb,
                       const float* __restrict__ weights,
                       float* __restrict__ cpart) {
    int sc = blockIdx.x, b = blockIdx.y, t = threadIdx.x;
    const f32x4* ep = (const f32x4*)emb;
    f32x4 acc = {0.f, 0.f, 0.f, 0.f};
    int s0 = sc * 128;
    for (int i = 0; i < 128; i += 4) {
#pragma unroll
        for (int u = 0; u < 4; ++u) {
            int s = s0 + i + u;
            float w = weights[b * S_LEN + s];
            f32x4 x = ep[(size_t)(s * NB + b) * 256 + t];
            acc += w * x;
        }
    }
    ((f32x4*)cpart)[(size_t)(sc * NB + b) * 256 + t] = acc;
}

// ---------------- K6: reduce partials -> context (d_out front)
__global__ void k_ctx2(const float* __restrict__ cpart, float* __restrict__ ctx) {
    int i = blockIdx.x * 256 + threadIdx.x;   // 32*1024
    float s = 0.f;
#pragma unroll
    for (int sc = 0; sc < 16; ++sc) s += cpart[sc * (NB * EMB) + i];
    ctx[i] = s;
}

extern "C" void kernel_launch(void* const* d_in, const int* in_sizes, int n_in,
                              void* d_out, int out_size, void* d_ws, size_t ws_size,
                              hipStream_t stream) {
    const float* hid   = (const float*)d_in[0];
    const float* emb   = (const float*)d_in[1];
    const float* W_hid = (const float*)d_in[2];
    const float* b_hid = (const float*)d_in[3];
    const float* W_emb = (const float*)d_in[4];
    const float* b_emb = (const float*)d_in[5];
    const float* att_v = (const float*)d_in[6];

    float* out     = (float*)d_out;
    float* ctx     = out;                // 32*1024
    float* weights = out + NB * EMB;     // 32*2048

    char* ws = (char*)d_ws;
    float*          part     = (float*)(ws);                    // 2 MiB (8 slices)
    float*          hid_comb = (float*)(ws + 2097152);          // 64 KiB
    unsigned short* WT       = (unsigned short*)(ws + 2162688); // 1 MiB
    float*          cpart    = (float*)(ws + 3211264);          // 2 MiB

    k_hidcomb<<<64, 256, 0, stream>>>(hid, W_hid, b_hid, b_emb, hid_comb);
    k_wt<<<dim3(32, 16), dim3(32, 8), 0, stream>>>(W_emb, WT);
    k_gemm_scores<<<512, 256, 0, stream>>>(emb, WT, hid_comb, att_v, part);
    k_softmax<<<NB, 256, 0, stream>>>(part, weights);
    k_ctx1<<<dim3(16, NB), 256, 0, stream>>>(emb, weights, cpart);
    k_ctx2<<<128, 256, 0, stream>>>(cpart, ctx);
}

// Round 7
// 269.716 us; speedup vs baseline: 1.6734x; 1.6734x over previous
//
#include <hip/hip_runtime.h>
#include <hip/hip_bf16.h>

#define S_LEN 2048
#define NB    32      // batch
#define EMB   1024
#define ATT   512
#define HID   1024

typedef float f32x4  __attribute__((ext_vector_type(4)));
typedef short s16x4  __attribute__((ext_vector_type(4)));
typedef short s16x8  __attribute__((ext_vector_type(8)));

static __device__ __forceinline__ short f2bf(float f) {
    return __builtin_bit_cast(short, __float2bfloat16(f));
}
static __device__ __forceinline__ float tanh_fast(float x) {
    float e = __expf(2.0f * x);
    return 1.0f - 2.0f / (e + 1.0f);
}

#define GLOAD_LDS16(gp, lp)                                                   \
    __builtin_amdgcn_global_load_lds(                                         \
        (const __attribute__((address_space(1))) void*)(gp),                  \
        (__attribute__((address_space(3))) void*)(uintptr_t)(lp), 16, 0, 0)

#define ORDER_FENCE() asm volatile("" ::: "memory")

// ---------------- K1: hid_comb[b][a] = hid[b,:]@W_hid[:,a] + b_hid[a] + b_emb[a]
__global__ void k_hidcomb(const float* __restrict__ hid,
                          const float* __restrict__ W_hid,
                          const float* __restrict__ b_hid,
                          const float* __restrict__ b_emb,
                          float* __restrict__ hid_comb) {
    int gid = blockIdx.x * 256 + threadIdx.x;   // 32*512 = 16384
    int b = gid >> 9, a = gid & 511;
    const float* hr = hid + b * HID;
    float acc = 0.f;
#pragma unroll 4
    for (int k = 0; k < HID; ++k) acc += hr[k] * W_hid[k * ATT + a];
    hid_comb[gid] = acc + b_hid[a] + b_emb[a];
}

// ---------------- K2: W_T[a][k] = bf16(W_emb[k][a])
__global__ void k_wt(const float* __restrict__ W, unsigned short* __restrict__ WT) {
    __shared__ float tile[32][33];
    int k0 = blockIdx.x * 32, a0 = blockIdx.y * 32;
    int tx = threadIdx.x, ty = threadIdx.y;     // 32 x 8
#pragma unroll
    for (int i = 0; i < 32; i += 8)
        tile[ty + i][tx] = W[(size_t)(k0 + ty + i) * ATT + a0 + tx];
    __syncthreads();
#pragma unroll
    for (int i = 0; i < 32; i += 8)
        WT[(size_t)(a0 + ty + i) * HID + k0 + tx] =
            (unsigned short)f2bf(tile[tx][ty + i]);
}

// ---------------- K3: m97-shaped 128x128 GEMM, A converted to bf16 in-flight.
// Body i: issue B(i+2) DMA + A(i+2) reg-loads; vmcnt(6) (A(i+1) ready, 6 newest
// stay in flight); cvt+ds_write A(i+1); 8x ds_read_b128 + 16 MFMA; lgkm+barrier.
// 2 A-bufs (bf16 8KB) + 3 B-bufs (8KB) = 40KB. 4 waves x (64x64).
__global__ __launch_bounds__(256, 3) void k_gemm_scores(
        const float* __restrict__ emb,
        const unsigned short* __restrict__ WT,
        const float* __restrict__ hid_comb,
        const float* __restrict__ att_v,
        float* __restrict__ part) {           // part[slice][b][s], slice=0..7
    __shared__ __align__(16) unsigned short lA[2 * 128 * 32];  // bf16, 8KB/buf
    __shared__ __align__(16) unsigned short lB[3 * 128 * 32];  // bf16, 8KB/buf

    // XCD swizzle: 2048 wgs, 8 XCDs; all 4 n-tiles of an m-panel on one XCD.
    int bid = blockIdx.x;
    int t2 = (bid & 7) * 256 + (bid >> 3);
    int mt = t2 >> 2, nt = t2 & 3;
    int m0 = mt * 128, n0 = nt * 128;

    int tid  = threadIdx.x;
    int lane = tid & 63, wave = tid >> 6;
    int wr = wave >> 1, wc = wave & 1;
    int row_l = lane & 15;        // fragment row (A) / col (B,D)
    int kg    = lane >> 4;        // k-group: k = kg*8 + i

    // ---- A staging map: 1024 16B-f32 chunks/tile; 4/thread -> 8B bf16 writes
    const float* aSrc[4];
    int aWoff[4];
#pragma unroll
    for (int j = 0; j < 4; ++j) {
        int c = j * 256 + tid;
        int r = c >> 3, pos = c & 7;
        aSrc[j]  = emb + (size_t)(m0 + r) * EMB + pos * 4;
        aWoff[j] = r * 64 + (((pos >> 1) ^ ((r >> 1) & 3)) * 16) + (pos & 1) * 8;
    }
    // ---- B staging map (pre-swizzled source, linear LDS dest)
    const unsigned short* bSrc[2];
    int bDst[2];
#pragma unroll
    for (int j = 0; j < 2; ++j) {
        int c = j * 256 + tid;
        int r = c >> 2, pos = c & 3;
        bSrc[j] = WT + (size_t)(n0 + r) * HID + (pos ^ ((r >> 1) & 3)) * 8;
        bDst[j] = c * 16;
    }
    // ---- fragment read byte-offsets (swizzled; proven 0-conflict pair)
    int aoff[4], boff[4];
#pragma unroll
    for (int mf = 0; mf < 4; ++mf) {
        int row = wr * 64 + mf * 16 + row_l;
        aoff[mf] = row * 64 + ((kg ^ ((row >> 1) & 3)) * 16);
    }
#pragma unroll
    for (int nf = 0; nf < 4; ++nf) {
        int row = wc * 64 + nf * 16 + row_l;
        boff[nf] = row * 64 + ((kg ^ ((row >> 1) & 3)) * 16);
    }

    f32x4 acc[4][4] = {};
    f32x4 S0[4], S1[4];           // two A-reg sets (static indexing only)
    char* lAB = (char*)lA;
    char* lBB = (char*)lB;

    // ---- prologue
#pragma unroll
    for (int j = 0; j < 4; ++j) S0[j] = *(const f32x4*)(aSrc[j]);     // A(0)
    ORDER_FENCE();
#pragma unroll
    for (int j = 0; j < 2; ++j) GLOAD_LDS16(bSrc[j], lBB + bDst[j]);  // B(0)
    ORDER_FENCE();
#pragma unroll
    for (int j = 0; j < 2; ++j) GLOAD_LDS16(bSrc[j] + 32, lBB + 8192 + bDst[j]); // B(1)
    asm volatile("s_waitcnt vmcnt(4)" ::: "memory");   // A(0) ready
#pragma unroll
    for (int j = 0; j < 4; ++j) {                      // write A(0) -> bufA0
        s16x4 w;
        w[0] = f2bf(S0[j][0]); w[1] = f2bf(S0[j][1]);
        w[2] = f2bf(S0[j][2]); w[3] = f2bf(S0[j][3]);
        *(s16x4*)(lAB + aWoff[j]) = w;
    }
    ORDER_FENCE();
#pragma unroll
    for (int j = 0; j < 4; ++j) S1[j] = *(const f32x4*)(aSrc[j] + 32); // A(1)
    asm volatile("s_waitcnt vmcnt(6)" ::: "memory");   // retire B(0); B(1),A(1) fly
    asm volatile("s_waitcnt lgkmcnt(0)\n\ts_barrier" ::: "memory");

    int kk = 0;        // current tile k-offset
    int bc = 0;        // B-buf of current tile
    int bn = 2;        // B-buf receiving tile i+2

#define GBODY(SET_W, SET_L, ABR, ABW)                                          \
    {                                                                          \
        int kb = (kk + 64) & 1023;               /* tile i+2 */                \
        _Pragma("unroll")                                                      \
        for (int j = 0; j < 2; ++j)              /* B(i+2) DMA */              \
            GLOAD_LDS16(bSrc[j] + kb, lBB + bn * 8192 + bDst[j]);              \
        _Pragma("unroll")                                                      \
        for (int j = 0; j < 4; ++j)              /* A(i+2) -> regs */          \
            SET_L[j] = *(const f32x4*)(aSrc[j] + kb);                          \
        asm volatile("s_waitcnt vmcnt(6)" ::: "memory"); /* A(i+1) ready */    \
        _Pragma("unroll")                                                      \
        for (int j = 0; j < 4; ++j) {            /* cvt+write A(i+1) */        \
            s16x4 w;                                                           \
            w[0] = f2bf(SET_W[j][0]); w[1] = f2bf(SET_W[j][1]);                \
            w[2] = f2bf(SET_W[j][2]); w[3] = f2bf(SET_W[j][3]);                \
            *(s16x4*)(lAB + (ABW) * 8192 + aWoff[j]) = w;                      \
        }                                                                      \
        const char* pa = lAB + (ABR) * 8192;                                   \
        const char* pb = lBB + bc * 8192;                                      \
        s16x8 af[4], bf[4];                                                    \
        _Pragma("unroll")                                                      \
        for (int mf = 0; mf < 4; ++mf)                                         \
            af[mf] = *(const s16x8*)(pa + aoff[mf]);                           \
        _Pragma("unroll")                                                      \
        for (int nf = 0; nf < 4; ++nf)                                         \
            bf[nf] = *(const s16x8*)(pb + boff[nf]);                           \
        _Pragma("unroll")                                                      \
        for (int mf = 0; mf < 4; ++mf)                                         \
            _Pragma("unroll")                                                  \
            for (int nf = 0; nf < 4; ++nf)                                     \
                acc[mf][nf] = __builtin_amdgcn_mfma_f32_16x16x32_bf16(         \
                    af[mf], bf[nf], acc[mf][nf], 0, 0, 0);                     \
        asm volatile("s_waitcnt lgkmcnt(0)\n\ts_barrier" ::: "memory");        \
        kk += 32;                                                              \
        bc = (bc == 2) ? 0 : bc + 1;                                           \
        bn = (bn == 2) ? 0 : bn + 1;                                           \
    }

    for (int it = 0; it < 16; ++it) {
        GBODY(S1, S0, 0, 1)    // body 2it:   read bufA0, write A(i+1)->bufA1
        GBODY(S0, S1, 1, 0)    // body 2it+1: read bufA1, write A(i+1)->bufA0
    }
#undef GBODY

    // ---- epilogue: score partial for this 64-col wave slice
    float vv[4];
#pragma unroll
    for (int nf = 0; nf < 4; ++nf)
        vv[nf] = att_v[n0 + wc * 64 + nf * 16 + row_l];

    int slice = nt * 2 + wc;
#pragma unroll
    for (int mf = 0; mf < 4; ++mf) {
#pragma unroll
        for (int j = 0; j < 4; ++j) {
            int m = m0 + wr * 64 + mf * 16 + kg * 4 + j;   // D row
            int b = m & 31;
            int s = m >> 5;
            const float* ad = hid_comb + b * ATT + n0 + wc * 64;
            float sum = 0.f;
#pragma unroll
            for (int nf = 0; nf < 4; ++nf) {
                float x = acc[mf][nf][j] + ad[nf * 16 + row_l];
                sum += tanh_fast(x) * vv[nf];
            }
#pragma unroll
            for (int d = 1; d < 16; d <<= 1)
                sum += __shfl_xor(sum, d, 64);
            if (row_l == 0)
                part[slice * (NB * S_LEN) + b * S_LEN + s] = sum;
        }
    }
}

// ---------------- K4: softmax over S per batch row (sums the 8 n-slices)
__global__ void k_softmax(const float* __restrict__ part,
                          float* __restrict__ weights) {
    int b = blockIdx.x, tid = threadIdx.x;  // 256 threads
    float v[8];
    float mx = -1e30f;
#pragma unroll
    for (int i = 0; i < 8; ++i) {
        int s = i * 256 + tid;
        float sc = 0.f;
#pragma unroll
        for (int p = 0; p < 8; ++p)
            sc += part[p * (NB * S_LEN) + b * S_LEN + s];
        v[i] = sc;
        mx = fmaxf(mx, sc);
    }
#pragma unroll
    for (int d = 1; d < 64; d <<= 1) mx = fmaxf(mx, __shfl_xor(mx, d, 64));
    __shared__ float sm[4], ss[4];
    if ((tid & 63) == 0) sm[tid >> 6] = mx;
    __syncthreads();
    mx = fmaxf(fmaxf(sm[0], sm[1]), fmaxf(sm[2], sm[3]));
    float sum = 0.f;
#pragma unroll
    for (int i = 0; i < 8; ++i) {
        v[i] = __expf(v[i] - mx);
        sum += v[i];
    }
#pragma unroll
    for (int d = 1; d < 64; d <<= 1) sum += __shfl_xor(sum, d, 64);
    if ((tid & 63) == 0) ss[tid >> 6] = sum;
    __syncthreads();
    sum = ss[0] + ss[1] + ss[2] + ss[3];
    float inv = 1.0f / sum;
#pragma unroll
    for (int i = 0; i < 8; ++i)
        weights[b * S_LEN + i * 256 + tid] = v[i] * inv;
}

// ---------------- K5: context partials over s-chunks (f32 emb)
__global__ void k_ctx1(const float* __restrict__ emb,
                       const float* __restrict__ weights,
                       float* __restrict__ cpart) {
    int sc = blockIdx.x, b = blockIdx.y, t = threadIdx.x;
    const f32x4* ep = (const f32x4*)emb;
    f32x4 acc = {0.f, 0.f, 0.f, 0.f};
    int s0 = sc * 128;
    for (int i = 0; i < 128; i += 4) {
#pragma unroll
        for (int u = 0; u < 4; ++u) {
            int s = s0 + i + u;
            float w = weights[b * S_LEN + s];
            f32x4 x = ep[(size_t)(s * NB + b) * 256 + t];
            acc += w * x;
        }
    }
    ((f32x4*)cpart)[(size_t)(sc * NB + b) * 256 + t] = acc;
}

// ---------------- K6: reduce partials -> context (d_out front)
__global__ void k_ctx2(const float* __restrict__ cpart, float* __restrict__ ctx) {
    int i = blockIdx.x * 256 + threadIdx.x;   // 32*1024
    float s = 0.f;
#pragma unroll
    for (int sc = 0; sc < 16; ++sc) s += cpart[sc * (NB * EMB) + i];
    ctx[i] = s;
}

extern "C" void kernel_launch(void* const* d_in, const int* in_sizes, int n_in,
                              void* d_out, int out_size, void* d_ws, size_t ws_size,
                              hipStream_t stream) {
    const float* hid   = (const float*)d_in[0];
    const float* emb   = (const float*)d_in[1];
    const float* W_hid = (const float*)d_in[2];
    const float* b_hid = (const float*)d_in[3];
    const float* W_emb = (const float*)d_in[4];
    const float* b_emb = (const float*)d_in[5];
    const float* att_v = (const float*)d_in[6];

    float* out     = (float*)d_out;
    float* ctx     = out;                // 32*1024
    float* weights = out + NB * EMB;     // 32*2048

    char* ws = (char*)d_ws;
    float*          part     = (float*)(ws);                    // 2 MiB (8 slices)
    float*          hid_comb = (float*)(ws + 2097152);          // 64 KiB
    unsigned short* WT       = (unsigned short*)(ws + 2162688); // 1 MiB
    float*          cpart    = (float*)(ws + 3211264);          // 2 MiB

    k_hidcomb<<<64, 256, 0, stream>>>(hid, W_hid, b_hid, b_emb, hid_comb);
    k_wt<<<dim3(32, 16), dim3(32, 8), 0, stream>>>(W_emb, WT);
    k_gemm_scores<<<2048, 256, 0, stream>>>(emb, WT, hid_comb, att_v, part);
    k_softmax<<<NB, 256, 0, stream>>>(part, weights);
    k_ctx1<<<dim3(16, NB), 256, 0, stream>>>(emb, weights, cpart);
    k_ctx2<<<128, 256, 0, stream>>>(cpart, ctx);
}

// Round 8
// 259.683 us; speedup vs baseline: 1.7381x; 1.0386x over previous
//
#include <hip/hip_runtime.h>
#include <hip/hip_bf16.h>

#define S_LEN 2048
#define NB    32      // batch
#define EMB   1024
#define ATT   512
#define HID   1024

typedef float f32x4  __attribute__((ext_vector_type(4)));
typedef short s16x4  __attribute__((ext_vector_type(4)));
typedef short s16x8  __attribute__((ext_vector_type(8)));

static __device__ __forceinline__ short f2bf(float f) {
    return __builtin_bit_cast(short, __float2bfloat16(f));
}
static __device__ __forceinline__ float tanh_fast(float x) {
    float e = __expf(2.0f * x);
    return 1.0f - 2.0f / (e + 1.0f);
}

#define GLOAD_LDS16(gp, lp)                                                   \
    __builtin_amdgcn_global_load_lds(                                         \
        (const __attribute__((address_space(1))) void*)(gp),                  \
        (__attribute__((address_space(3))) void*)(uintptr_t)(lp), 16, 0, 0)

#define ORDER_FENCE() asm volatile("" ::: "memory")

// ---------------- K1: hid_comb[b][a] = hid[b,:]@W_hid[:,a] + b_hid[a] + b_emb[a]
__global__ void k_hidcomb(const float* __restrict__ hid,
                          const float* __restrict__ W_hid,
                          const float* __restrict__ b_hid,
                          const float* __restrict__ b_emb,
                          float* __restrict__ hid_comb) {
    int gid = blockIdx.x * 256 + threadIdx.x;   // 32*512 = 16384
    int b = gid >> 9, a = gid & 511;
    const float* hr = hid + b * HID;
    float acc = 0.f;
#pragma unroll 4
    for (int k = 0; k < HID; ++k) acc += hr[k] * W_hid[k * ATT + a];
    hid_comb[gid] = acc + b_hid[a] + b_emb[a];
}

// ---------------- K2: W_T[a][k] = bf16(W_emb[k][a])
__global__ void k_wt(const float* __restrict__ W, unsigned short* __restrict__ WT) {
    __shared__ float tile[32][33];
    int k0 = blockIdx.x * 32, a0 = blockIdx.y * 32;
    int tx = threadIdx.x, ty = threadIdx.y;     // 32 x 8
#pragma unroll
    for (int i = 0; i < 32; i += 8)
        tile[ty + i][tx] = W[(size_t)(k0 + ty + i) * ATT + a0 + tx];
    __syncthreads();
#pragma unroll
    for (int i = 0; i < 32; i += 8)
        WT[(size_t)(a0 + ty + i) * HID + k0 + tx] =
            (unsigned short)f2bf(tile[tx][ty + i]);
}

// ---------------- K3: 256x256 8-phase-template GEMM (T2+T3+T4+T5+T14).
// 512 thr = 8 waves (2M x 4N), per-wave 128x64. BK=64, 16 K-tiles, 4 phases
// per K-tile. B via global_load_lds (pre-swizzled src); A f32->reg->cvt->
// swizzled ds_write (regs live one K-tile). All waits counted vmcnt(8).
// Fused tanh + dot(att_v) epilogue -> 8 score slices (no atomics).
__global__ __launch_bounds__(512) void k_gemm_scores(
        const float* __restrict__ emb,
        const unsigned short* __restrict__ WT,
        const float* __restrict__ hid_comb,
        const float* __restrict__ att_v,
        float* __restrict__ part) {
    // layout: [bufA0 32K][bufA1 32K][bufB0 32K][bufB1 32K]  (tiles [256][64]bf16)
    __shared__ __align__(16) unsigned short ldsbuf[65536];   // 128 KB
    char* L = (char*)ldsbuf;

    int bid = blockIdx.x;                 // 512 wgs: 256 m-tiles x 2 n-tiles
    int t2  = (bid & 7) * 64 + (bid >> 3);   // XCD swizzle (512%8==0, bijective)
    int mt  = t2 >> 1, nt = t2 & 1;
    int m0  = mt * 256, n0 = nt * 256;

    int tid  = threadIdx.x;
    int lane = tid & 63, w = tid >> 6;
    int wm = w >> 2, wn = w & 3;          // wave tile: rows wm*128, cols wn*64
    int row_l = lane & 15, kg = lane >> 4;

    // ---- A staging: thread covers 2 16B-bf16 chunks (= 64B f32 contiguous)
    int arow = tid >> 2;                  // row within 128-row half
    int apos = (tid & 3) * 2;             // chunk pos 0,2,4,6
    const float* aG = emb + (size_t)(m0 + arow) * EMB + apos * 8;
    int aw0 = arow * 128 + ((apos ^ (arow & 7)) * 16);
    int aw1 = arow * 128 + (((apos + 1) ^ (arow & 7)) * 16);

    // ---- B staging: 4 gload_lds calls per K-tile (2 halves x 2)
    int brow = tid >> 3;                  // 0..63
    int bpos = tid & 7;
    const unsigned short* bG = WT + (size_t)(n0 + brow) * HID + (bpos ^ (brow & 7)) * 8;
    int bdst = tid * 16;

    // ---- fragment read offsets (XOR term reduces to per-thread constant)
    int arow_r[8], brow_r[4], cx[2];
#pragma unroll
    for (int mf = 0; mf < 8; ++mf) arow_r[mf] = (wm * 128 + mf * 16 + row_l) * 128;
#pragma unroll
    for (int nf = 0; nf < 4; ++nf) brow_r[nf] = (wn * 64 + nf * 16 + row_l) * 128;
#pragma unroll
    for (int ks = 0; ks < 2; ++ks) cx[ks] = (((ks * 4 + kg) ^ (row_l & 7)) * 16);

    f32x4 acc[8][4] = {};
    f32x4 Rh0[4], Rh1[4];                 // A stage regs (static names, 1-tile life)
    s16x8 bf[4][2];

#define CVT_WRITE(RH, DSTOFF)                                                 \
    {                                                                         \
        s16x8 v0, v1;                                                         \
        v0[0] = f2bf(RH[0][0]); v0[1] = f2bf(RH[0][1]);                       \
        v0[2] = f2bf(RH[0][2]); v0[3] = f2bf(RH[0][3]);                       \
        v0[4] = f2bf(RH[1][0]); v0[5] = f2bf(RH[1][1]);                       \
        v0[6] = f2bf(RH[1][2]); v0[7] = f2bf(RH[1][3]);                       \
        v1[0] = f2bf(RH[2][0]); v1[1] = f2bf(RH[2][1]);                       \
        v1[2] = f2bf(RH[2][2]); v1[3] = f2bf(RH[2][3]);                       \
        v1[4] = f2bf(RH[3][0]); v1[5] = f2bf(RH[3][1]);                       \
        v1[6] = f2bf(RH[3][2]); v1[7] = f2bf(RH[3][3]);                       \
        *(s16x8*)(L + (DSTOFF) + aw0) = v0;                                   \
        *(s16x8*)(L + (DSTOFF) + aw1) = v1;                                   \
    }

#define MFMA_CLUSTER(MFB)                                                     \
    _Pragma("unroll")                                                         \
    for (int ml = 0; ml < 2; ++ml)                                            \
        _Pragma("unroll")                                                     \
        for (int nf = 0; nf < 4; ++nf)                                        \
            _Pragma("unroll")                                                 \
            for (int ks = 0; ks < 2; ++ks)                                    \
                acc[(MFB) + ml][nf] = __builtin_amdgcn_mfma_f32_16x16x32_bf16(\
                    af[ml][ks], bf[nf][ks], acc[(MFB) + ml][nf], 0, 0, 0);

    // ---------------- prologue ----------------
#pragma unroll
    for (int i = 0; i < 4; ++i) Rh0[i] = *(const f32x4*)(aG + i * 4);            // A(0)h0
#pragma unroll
    for (int i = 0; i < 4; ++i) Rh1[i] = *(const f32x4*)(aG + 128 * EMB + i * 4);// A(0)h1
    ORDER_FENCE();
    GLOAD_LDS16(bG,             L + 65536 + bdst);             // B(0) h0 j0
    GLOAD_LDS16(bG +  64 * HID, L + 65536 +  8192 + bdst);     // B(0) h0 j1
    GLOAD_LDS16(bG + 128 * HID, L + 65536 + 16384 + bdst);     // B(0) h1 j0
    GLOAD_LDS16(bG + 192 * HID, L + 65536 + 24576 + bdst);     // B(0) h1 j1
    ORDER_FENCE();
    asm volatile("s_waitcnt vmcnt(4)" ::: "memory");           // A(0) regs ready
    CVT_WRITE(Rh0, 0)                                          // A(0)h0 -> bufA0
    CVT_WRITE(Rh1, 16384)                                      // A(0)h1 -> bufA0
    ORDER_FENCE();
#pragma unroll
    for (int i = 0; i < 4; ++i) Rh0[i] = *(const f32x4*)(aG + 64 + i * 4);            // A(1)h0
#pragma unroll
    for (int i = 0; i < 4; ++i) Rh1[i] = *(const f32x4*)(aG + 128 * EMB + 64 + i * 4);// A(1)h1
    ORDER_FENCE();
    asm volatile("s_waitcnt vmcnt(8) lgkmcnt(0)\n\ts_barrier" ::: "memory"); // B(0) done

    // ---------------- main loop: 16 K-tiles x 4 phases ----------------
    for (int t = 0; t < 16; ++t) {
        int bt  = (t & 1) * 32768;
        int bn  = ((t + 1) & 1) * 32768;
        int ktn = ((t + 1) & 15) * 64;    // B stage k-offset (wraps at tail)
        int kta = ((t + 2) & 15) * 64;    // A stage k-offset (wraps at tail)

        // ---- P0: issue B(t+1)h0; read B frags (8) + A mf0,1; MFMA
        GLOAD_LDS16(bG + ktn,            L + 65536 + bn + bdst);
        GLOAD_LDS16(bG + 64 * HID + ktn, L + 65536 + bn + 8192 + bdst);
        ORDER_FENCE();
        {
            s16x8 af[2][2];
#pragma unroll
            for (int nf = 0; nf < 4; ++nf)
#pragma unroll
                for (int ks = 0; ks < 2; ++ks)
                    bf[nf][ks] = *(const s16x8*)(L + 65536 + bt + brow_r[nf] + cx[ks]);
#pragma unroll
            for (int ml = 0; ml < 2; ++ml)
#pragma unroll
                for (int ks = 0; ks < 2; ++ks)
                    af[ml][ks] = *(const s16x8*)(L + bt + arow_r[ml] + cx[ks]);
            asm volatile("s_barrier\n\ts_waitcnt lgkmcnt(0)" ::: "memory");
            __builtin_amdgcn_s_setprio(1);
            MFMA_CLUSTER(0)
            __builtin_amdgcn_s_setprio(0);
            asm volatile("s_barrier" ::: "memory");
        }
        // ---- P1: issue B(t+1)h1; read A mf2,3; MFMA
        GLOAD_LDS16(bG + 128 * HID + ktn, L + 65536 + bn + 16384 + bdst);
        GLOAD_LDS16(bG + 192 * HID + ktn, L + 65536 + bn + 24576 + bdst);
        ORDER_FENCE();
        {
            s16x8 af[2][2];
#pragma unroll
            for (int ml = 0; ml < 2; ++ml)
#pragma unroll
                for (int ks = 0; ks < 2; ++ks)
                    af[ml][ks] = *(const s16x8*)(L + bt + arow_r[2 + ml] + cx[ks]);
            asm volatile("s_barrier\n\ts_waitcnt lgkmcnt(0)" ::: "memory");
            __builtin_amdgcn_s_setprio(1);
            MFMA_CLUSTER(2)
            __builtin_amdgcn_s_setprio(0);
            asm volatile("s_barrier" ::: "memory");
        }
        // ---- P2: retire Rh0-old (vmcnt 8); cvt+write A(t+1)h0; reload Rh0(t+2)h0;
        //          read A mf4,5; MFMA
        asm volatile("s_waitcnt vmcnt(8)" ::: "memory");
        CVT_WRITE(Rh0, bn)
        ORDER_FENCE();
#pragma unroll
        for (int i = 0; i < 4; ++i) Rh0[i] = *(const f32x4*)(aG + kta + i * 4);
        ORDER_FENCE();
        {
            s16x8 af[2][2];
#pragma unroll
            for (int ml = 0; ml < 2; ++ml)
#pragma unroll
                for (int ks = 0; ks < 2; ++ks)
                    af[ml][ks] = *(const s16x8*)(L + bt + arow_r[4 + ml] + cx[ks]);
            asm volatile("s_waitcnt lgkmcnt(0)\n\ts_barrier" ::: "memory");
            __builtin_amdgcn_s_setprio(1);
            MFMA_CLUSTER(4)
            __builtin_amdgcn_s_setprio(0);
            asm volatile("s_barrier" ::: "memory");
        }
        // ---- P3: same for h1; trailing vmcnt(8) retires B(t+1) before barrier
        asm volatile("s_waitcnt vmcnt(8)" ::: "memory");
        CVT_WRITE(Rh1, bn + 16384)
        ORDER_FENCE();
#pragma unroll
        for (int i = 0; i < 4; ++i) Rh1[i] = *(const f32x4*)(aG + 128 * EMB + kta + i * 4);
        ORDER_FENCE();
        {
            s16x8 af[2][2];
#pragma unroll
            for (int ml = 0; ml < 2; ++ml)
#pragma unroll
                for (int ks = 0; ks < 2; ++ks)
                    af[ml][ks] = *(const s16x8*)(L + bt + arow_r[6 + ml] + cx[ks]);
            asm volatile("s_waitcnt lgkmcnt(0) vmcnt(8)\n\ts_barrier" ::: "memory");
            __builtin_amdgcn_s_setprio(1);
            MFMA_CLUSTER(6)
            __builtin_amdgcn_s_setprio(0);
            asm volatile("s_barrier" ::: "memory");
        }
    }
#undef CVT_WRITE
#undef MFMA_CLUSTER

    // ---------------- epilogue: tanh + dot(att_v) + 16-lane reduce ----------------
    float vv[4];
#pragma unroll
    for (int nf = 0; nf < 4; ++nf)
        vv[nf] = att_v[n0 + wn * 64 + nf * 16 + row_l];

    int slice = nt * 4 + wn;
#pragma unroll
    for (int mf = 0; mf < 8; ++mf) {
#pragma unroll
        for (int j = 0; j < 4; ++j) {
            int m = m0 + wm * 128 + mf * 16 + kg * 4 + j;   // D row
            int b = m & 31;
            int s = m >> 5;
            const float* ad = hid_comb + b * ATT + n0 + wn * 64;
            float sum = 0.f;
#pragma unroll
            for (int nf = 0; nf < 4; ++nf) {
                float xv = acc[mf][nf][j] + ad[nf * 16 + row_l];
                sum += tanh_fast(xv) * vv[nf];
            }
#pragma unroll
            for (int d = 1; d < 16; d <<= 1)
                sum += __shfl_xor(sum, d, 64);
            if (row_l == 0)
                part[slice * (NB * S_LEN) + b * S_LEN + s] = sum;
        }
    }
}

// ---------------- K4: softmax over S per batch row (sums the 8 n-slices)
__global__ void k_softmax(const float* __restrict__ part,
                          float* __restrict__ weights) {
    int b = blockIdx.x, tid = threadIdx.x;  // 256 threads
    float v[8];
    float mx = -1e30f;
#pragma unroll
    for (int i = 0; i < 8; ++i) {
        int s = i * 256 + tid;
        float sc = 0.f;
#pragma unroll
        for (int p = 0; p < 8; ++p)
            sc += part[p * (NB * S_LEN) + b * S_LEN + s];
        v[i] = sc;
        mx = fmaxf(mx, sc);
    }
#pragma unroll
    for (int d = 1; d < 64; d <<= 1) mx = fmaxf(mx, __shfl_xor(mx, d, 64));
    __shared__ float sm[4], ss[4];
    if ((tid & 63) == 0) sm[tid >> 6] = mx;
    __syncthreads();
    mx = fmaxf(fmaxf(sm[0], sm[1]), fmaxf(sm[2], sm[3]));
    float sum = 0.f;
#pragma unroll
    for (int i = 0; i < 8; ++i) {
        v[i] = __expf(v[i] - mx);
        sum += v[i];
    }
#pragma unroll
    for (int d = 1; d < 64; d <<= 1) sum += __shfl_xor(sum, d, 64);
    if ((tid & 63) == 0) ss[tid >> 6] = sum;
    __syncthreads();
    sum = ss[0] + ss[1] + ss[2] + ss[3];
    float inv = 1.0f / sum;
#pragma unroll
    for (int i = 0; i < 8; ++i)
        weights[b * S_LEN + i * 256 + tid] = v[i] * inv;
}

// ---------------- K5: context partials over s-chunks (f32 emb)
__global__ void k_ctx1(const float* __restrict__ emb,
                       const float* __restrict__ weights,
                       float* __restrict__ cpart) {
    int sc = blockIdx.x, b = blockIdx.y, t = threadIdx.x;
    const f32x4* ep = (const f32x4*)emb;
    f32x4 acc = {0.f, 0.f, 0.f, 0.f};
    int s0 = sc * 128;
    for (int i = 0; i < 128; i += 4) {
#pragma unroll
        for (int u = 0; u < 4; ++u) {
            int s = s0 + i + u;
            float w = weights[b * S_LEN + s];
            f32x4 x = ep[(size_t)(s * NB + b) * 256 + t];
            acc += w * x;
        }
    }
    ((f32x4*)cpart)[(size_t)(sc * NB + b) * 256 + t] = acc;
}

// ---------------- K6: reduce partials -> context (d_out front)
__global__ void k_ctx2(const float* __restrict__ cpart, float* __restrict__ ctx) {
    int i = blockIdx.x * 256 + threadIdx.x;   // 32*1024
    float s = 0.f;
#pragma unroll
    for (int sc = 0; sc < 16; ++sc) s += cpart[sc * (NB * EMB) + i];
    ctx[i] = s;
}

extern "C" void kernel_launch(void* const* d_in, const int* in_sizes, int n_in,
                              void* d_out, int out_size, void* d_ws, size_t ws_size,
                              hipStream_t stream) {
    const float* hid   = (const float*)d_in[0];
    const float* emb   = (const float*)d_in[1];
    const float* W_hid = (const float*)d_in[2];
    const float* b_hid = (const float*)d_in[3];
    const float* W_emb = (const float*)d_in[4];
    const float* b_emb = (const float*)d_in[5];
    const float* att_v = (const float*)d_in[6];

    float* out     = (float*)d_out;
    float* ctx     = out;                // 32*1024
    float* weights = out + NB * EMB;     // 32*2048

    char* ws = (char*)d_ws;
    float*          part     = (float*)(ws);                    // 2 MiB (8 slices)
    float*          hid_comb = (float*)(ws + 2097152);          // 64 KiB
    unsigned short* WT       = (unsigned short*)(ws + 2162688); // 1 MiB
    float*          cpart    = (float*)(ws + 3211264);          // 2 MiB

    k_hidcomb<<<64, 256, 0, stream>>>(hid, W_hid, b_hid, b_emb, hid_comb);
    k_wt<<<dim3(32, 16), dim3(32, 8), 0, stream>>>(W_emb, WT);
    k_gemm_scores<<<512, 512, 0, stream>>>(emb, WT, hid_comb, att_v, part);
    k_softmax<<<NB, 256, 0, stream>>>(part, weights);
    k_ctx1<<<dim3(16, NB), 256, 0, stream>>>(emb, weights, cpart);
    k_ctx2<<<128, 256, 0, stream>>>(cpart, ctx);
}